// Round 7
// baseline (158.434 us; speedup 1.0000x reference)
//
#include <hip/hip_runtime.h>

// Problem constants: B=64, NIN=512, H1=1024, H2=1024, NOUT=512, COND=64, FC=1.
#define BB    64
#define NIN   512
#define H1D   1024
#define H2D   1024
#define NOUTD 512
#define CONDD 64
#define L2E   1.4426950408889634f   // log2(e)

// ---------------------------------------------------------------------------
// Prep kernel (identical to R4):
//   blocks [0,320): six cond GEMMs, 16 rows/block (4 rows/wave), rows
//                   concatenated [A0|C0|A1|C1|A2|C2] = 5120 rows.
//                   A-rows stored prescaled by log2(e) into AX .x (stride 2).
//   blocks [320,328): x transpose tiles -> AX0 .y
// ---------------------------------------------------------------------------
__global__ __launch_bounds__(256) void prep_kernel(
    const float* __restrict__ x,  const float* __restrict__ u,
    const float* __restrict__ a0w, const float* __restrict__ a0b,
    const float* __restrict__ b0w, const float* __restrict__ b0b,
    const float* __restrict__ a1w, const float* __restrict__ a1b,
    const float* __restrict__ b1w, const float* __restrict__ b1b,
    const float* __restrict__ a2w, const float* __restrict__ a2b,
    const float* __restrict__ b2w, const float* __restrict__ b2b,
    float* __restrict__ AX0, float* __restrict__ AX1, float* __restrict__ AX2,
    float* __restrict__ C0t, float* __restrict__ C1t, float* __restrict__ C2t)
{
    __shared__ float lds[64 * 65];
    const int tid = threadIdx.x;
    const int bid = blockIdx.x;

    if (bid < 320) {
        for (int e = tid; e < BB * CONDD; e += 256)
            lds[(e & 63) * 65 + (e >> 6)] = u[e];
        __syncthreads();

        const int b   = tid & 63;
        const int wid = __builtin_amdgcn_readfirstlane(tid >> 6);
        const int r0  = bid * 16 + wid * 4;

        const float* w; const float* bias; float* out; int stride; float scale; int lr0;
        if      (r0 <  512) { w = a0w; bias = a0b; out = AX0; stride = 2; scale = L2E; lr0 = r0;        }
        else if (r0 < 1536) { w = b0w; bias = b0b; out = C0t; stride = 1; scale = 1.f; lr0 = r0 -  512; }
        else if (r0 < 2560) { w = a1w; bias = a1b; out = AX1; stride = 2; scale = L2E; lr0 = r0 - 1536; }
        else if (r0 < 3584) { w = b1w; bias = b1b; out = C1t; stride = 1; scale = 1.f; lr0 = r0 - 2560; }
        else if (r0 < 4608) { w = a2w; bias = a2b; out = AX2; stride = 2; scale = L2E; lr0 = r0 - 3584; }
        else                { w = b2w; bias = b2b; out = C2t; stride = 1; scale = 1.f; lr0 = r0 - 4608; }

        const float* __restrict__ w0 = w + (lr0 + 0) * CONDD;
        const float* __restrict__ w1 = w + (lr0 + 1) * CONDD;
        const float* __restrict__ w2 = w + (lr0 + 2) * CONDD;
        const float* __restrict__ w3 = w + (lr0 + 3) * CONDD;
        float acc0 = bias[lr0 + 0], acc1 = bias[lr0 + 1];
        float acc2 = bias[lr0 + 2], acc3 = bias[lr0 + 3];
        #pragma unroll
        for (int k = 0; k < CONDD; ++k) {
            const float uv = lds[k * 65 + b];
            acc0 = fmaf(w0[k], uv, acc0);
            acc1 = fmaf(w1[k], uv, acc1);
            acc2 = fmaf(w2[k], uv, acc2);
            acc3 = fmaf(w3[k], uv, acc3);
        }
        out[((lr0 + 0) * 64 + b) * stride] = acc0 * scale;
        out[((lr0 + 1) * 64 + b) * stride] = acc1 * scale;
        out[((lr0 + 2) * 64 + b) * stride] = acc2 * scale;
        out[((lr0 + 3) * 64 + b) * stride] = acc3 * scale;
    } else {
        const int i0 = (bid - 320) * 64;
        for (int e = tid; e < 64 * 64; e += 256) {
            int r = e >> 6, c = e & 63;                // r=b, c=i offset
            lds[c * 65 + r] = x[r * NIN + i0 + c];
        }
        __syncthreads();
        for (int e = tid; e < 64 * 64; e += 256) {
            int r = e >> 6, c = e & 63;                // r=i offset, c=b
            AX0[((i0 + r) * 64 + c) * 2 + 1] = lds[r * 65 + c];
        }
    }
}

// ---------------------------------------------------------------------------
// Branchless gated masked matvec (R4 body, OT o's per block, 8 waves split I):
//   out[o,b] = sum_i 1/(1+2^(-A'[i,b]*Ct[o,b])) * m[o,i]*W[o,i] * X[i,b]
// ---------------------------------------------------------------------------
template<int I, int OT, bool FINAL>
__device__ __forceinline__ void gated_body(
    const float2* __restrict__ AX, const float* __restrict__ Ct,
    const float*  __restrict__ M,  const float* __restrict__ W,
    float* __restrict__ out)
{
    constexpr int ICW = I / 8;                  // i extent per wave
    const int tid = threadIdx.x;
    const int b   = tid & 63;
    const int wid = __builtin_amdgcn_readfirstlane(tid >> 6);   // 0..7 uniform
    const int o0  = blockIdx.x * OT;
    const int ibase = wid * ICW;

    float cc[OT], acc[OT];
    const float* __restrict__ mrow[OT];
    const float* __restrict__ wrow[OT];
    #pragma unroll
    for (int oo = 0; oo < OT; ++oo) {
        cc[oo]   = Ct[(o0 + oo) * 64 + b];
        mrow[oo] = M + (size_t)(o0 + oo) * I + ibase;
        wrow[oo] = W + (size_t)(o0 + oo) * I + ibase;
        acc[oo]  = 0.f;
    }
    const float2* __restrict__ axp = AX + (size_t)ibase * 64 + b;

    #pragma unroll 8
    for (int ii = 0; ii < ICW; ++ii) {
        const float2 ax = axp[(size_t)ii * 64];
        #pragma unroll
        for (int oo = 0; oo < OT; ++oo) {
            const float mw = mrow[oo][ii] * wrow[oo][ii];
            const float t  = __builtin_amdgcn_exp2f(-(ax.x * cc[oo]));
            const float s  = __builtin_amdgcn_rcpf(1.f + t);    // inf-safe: ->0
            acc[oo] = fmaf(s, mw * ax.y, acc[oo]);
        }
    }

    __shared__ float red[8][OT][64];
    #pragma unroll
    for (int oo = 0; oo < OT; ++oo) red[wid][oo][b] = acc[oo];
    __syncthreads();
    if (tid < OT * 64) {
        const int oo = tid >> 6, bb = tid & 63;
        float v = 0.f;
        #pragma unroll
        for (int w8 = 0; w8 < 8; ++w8) v += red[w8][oo][bb];
        if (FINAL) out[bb * NOUTD + (o0 + oo)] = v;             // (B, NOUT)
        else       out[((o0 + oo) * 64 + bb) * 2 + 1] = v;      // next AX .y
    }
}

// ---------------------------------------------------------------------------
// Layer 1 with mask-prefix sparsity. MADE m0 rows are ones-prefixes of
// length d1[o] (~50% density). Compute the EXACT last-nonzero index per row
// (no assumption on structure), then bound each (wave, row) loop by it.
// oo-outer so each row stops at its own cutoff; ax re-reads hit L1.
// ---------------------------------------------------------------------------
__global__ __launch_bounds__(512) void gated_l1(
    const float2* __restrict__ AX, const float* __restrict__ Ct,
    const float* __restrict__ M, const float* __restrict__ W,
    float* __restrict__ out)
{
    constexpr int I = NIN, OT = 4, ICW = I / 8;
    const int tid = threadIdx.x;
    const int b   = tid & 63;
    const int wid = __builtin_amdgcn_readfirstlane(tid >> 6);
    const int o0  = blockIdx.x * OT;
    const int ibase = wid * ICW;

    __shared__ int cut[OT];
    if (tid < OT) cut[tid] = 0;
    __syncthreads();
    #pragma unroll
    for (int oo = 0; oo < OT; ++oo) {
        // blockDim == I == 512: one coalesced element per thread
        const float mv = M[(size_t)(o0 + oo) * I + tid];
        int cand = (mv != 0.f) ? (tid + 1) : 0;
        #pragma unroll
        for (int s = 32; s > 0; s >>= 1)
            cand = max(cand, __shfl_xor(cand, s, 64));
        if ((tid & 63) == 0) atomicMax(&cut[oo], cand);
    }
    __syncthreads();

    float acc[OT];
    const float2* __restrict__ axp = AX + (size_t)ibase * 64 + b;
    #pragma unroll
    for (int oo = 0; oo < OT; ++oo) {
        const float cc = Ct[(o0 + oo) * 64 + b];
        const float* __restrict__ mrow = M + (size_t)(o0 + oo) * I + ibase;
        const float* __restrict__ wrow = W + (size_t)(o0 + oo) * I + ibase;
        const int end = min(max(cut[oo] - ibase, 0), ICW);   // wave-uniform
        float a = 0.f;
        #pragma unroll 8
        for (int ii = 0; ii < end; ++ii) {
            const float2 ax = axp[(size_t)ii * 64];
            const float mw = mrow[ii] * wrow[ii];
            const float t  = __builtin_amdgcn_exp2f(-(ax.x * cc));
            const float s  = __builtin_amdgcn_rcpf(1.f + t);
            a = fmaf(s, mw * ax.y, a);
        }
        acc[oo] = a;
    }

    __shared__ float red[8][OT][64];
    #pragma unroll
    for (int oo = 0; oo < OT; ++oo) red[wid][oo][b] = acc[oo];
    __syncthreads();
    if (tid < OT * 64) {
        const int oo = tid >> 6, bb = tid & 63;
        float v = 0.f;
        #pragma unroll
        for (int w8 = 0; w8 < 8; ++w8) v += red[w8][oo][bb];
        out[((o0 + oo) * 64 + bb) * 2 + 1] = v;               // AX1 .y
    }
}

__global__ __launch_bounds__(512) void gated_l2(
    const float2* __restrict__ AX, const float* __restrict__ Ct,
    const float* __restrict__ M, const float* __restrict__ W, float* __restrict__ out)
{ gated_body<H1D, 4, false>(AX, Ct, M, W, out); }

__global__ __launch_bounds__(512) void gated_l3(
    const float2* __restrict__ AX, const float* __restrict__ Ct,
    const float* __restrict__ M, const float* __restrict__ W, float* __restrict__ out)
{ gated_body<H2D, 2, true>(AX, Ct, M, W, out); }

// ---------------------------------------------------------------------------
extern "C" void kernel_launch(void* const* d_in, const int* in_sizes, int n_in,
                              void* d_out, int out_size, void* d_ws, size_t ws_size,
                              hipStream_t stream) {
    (void)in_sizes; (void)n_in; (void)out_size; (void)ws_size;
    const float* x   = (const float*)d_in[0];
    const float* u   = (const float*)d_in[1];
    const float* m0  = (const float*)d_in[2];
    const float* m1  = (const float*)d_in[3];
    const float* m2  = (const float*)d_in[4];
    const float* W0  = (const float*)d_in[5];
    const float* W1  = (const float*)d_in[6];
    const float* W2  = (const float*)d_in[7];
    const float* a0w = (const float*)d_in[8];  const float* a0b = (const float*)d_in[9];
    const float* b0w = (const float*)d_in[10]; const float* b0b = (const float*)d_in[11];
    const float* a1w = (const float*)d_in[12]; const float* a1b = (const float*)d_in[13];
    const float* b1w = (const float*)d_in[14]; const float* b1b = (const float*)d_in[15];
    const float* a2w = (const float*)d_in[16]; const float* a2b = (const float*)d_in[17];
    const float* b2w = (const float*)d_in[18]; const float* b2b = (const float*)d_in[19];

    float* ws  = (float*)d_ws;                 // offsets in floats
    float* AX0 = ws;                           // float2[512*64]   = 65536
    float* AX1 = ws + 65536;                   // float2[1024*64]  = 131072
    float* AX2 = ws + 196608;                  // float2[1024*64]  = 131072
    float* C0t = ws + 327680;                  // 1024*64 = 65536
    float* C1t = ws + 393216;                  // 1024*64 = 65536
    float* C2t = ws + 458752;                  // 512*64  = 32768
    float* out = (float*)d_out;

    prep_kernel<<<328, 256, 0, stream>>>(x, u,
        a0w, a0b, b0w, b0b, a1w, a1b, b1w, b1b, a2w, a2b, b2w, b2b,
        AX0, AX1, AX2, C0t, C1t, C2t);

    // L1: I=512,  O=1024, OT=4, prefix-sparse -> 256 blocks; writes AX1 .y
    gated_l1<<<H1D / 4,   512, 0, stream>>>((const float2*)AX0, C0t, m0, W0, AX1);
    // L2: I=1024, O=1024, OT=4 -> 256 blocks; writes AX2 .y
    gated_l2<<<H2D / 4,   512, 0, stream>>>((const float2*)AX1, C1t, m1, W1, AX2);
    // L3: I=1024, O=512,  OT=2 -> 256 blocks; writes d_out (B, NOUT)
    gated_l3<<<NOUTD / 2, 512, 0, stream>>>((const float2*)AX2, C2t, m2, W2, out);
}

// Round 8
// 152.601 us; speedup vs baseline: 1.0382x; 1.0382x over previous
//
#include <hip/hip_runtime.h>

// Problem constants: B=64, NIN=512, H1=1024, H2=1024, NOUT=512, COND=64, FC=1.
// FINAL CONFIG (best measured: 152.1 us, R4). Decomposition: ~127 us harness
// reset overhead (268 MB ws poison fill @ ~42 us + restores + replay) +
// ~25 us kernels vs ~20 us transcendental-issue floor (134M sigmoids,
// exp2+rcp quarter-rate). R5 (cooperative fusion), R6 (2x occupancy),
// R7 (L1 mask-prefix sparsity) all neutral or negative.
#define BB    64
#define NIN   512
#define H1D   1024
#define H2D   1024
#define NOUTD 512
#define CONDD 64
#define L2E   1.4426950408889634f   // log2(e)

// ---------------------------------------------------------------------------
// Prep kernel:
//   blocks [0,320): six cond GEMMs, 16 rows/block (4 rows/wave), rows
//                   concatenated [A0|C0|A1|C1|A2|C2] = 5120 rows.
//                   A-rows stored prescaled by log2(e) into AX .x (stride 2).
//   blocks [320,328): x transpose tiles -> AX0 .y
// ---------------------------------------------------------------------------
__global__ __launch_bounds__(256) void prep_kernel(
    const float* __restrict__ x,  const float* __restrict__ u,
    const float* __restrict__ a0w, const float* __restrict__ a0b,
    const float* __restrict__ b0w, const float* __restrict__ b0b,
    const float* __restrict__ a1w, const float* __restrict__ a1b,
    const float* __restrict__ b1w, const float* __restrict__ b1b,
    const float* __restrict__ a2w, const float* __restrict__ a2b,
    const float* __restrict__ b2w, const float* __restrict__ b2b,
    float* __restrict__ AX0, float* __restrict__ AX1, float* __restrict__ AX2,
    float* __restrict__ C0t, float* __restrict__ C1t, float* __restrict__ C2t)
{
    __shared__ float lds[64 * 65];
    const int tid = threadIdx.x;
    const int bid = blockIdx.x;

    if (bid < 320) {
        // stage u transposed: lds[k*65+b] = u[b*64+k]
        for (int e = tid; e < BB * CONDD; e += 256)
            lds[(e & 63) * 65 + (e >> 6)] = u[e];
        __syncthreads();

        const int b   = tid & 63;
        const int wid = __builtin_amdgcn_readfirstlane(tid >> 6);
        const int r0  = bid * 16 + wid * 4;          // 4 rows/wave, same segment

        const float* w; const float* bias; float* out; int stride; float scale; int lr0;
        if      (r0 <  512) { w = a0w; bias = a0b; out = AX0; stride = 2; scale = L2E; lr0 = r0;        }
        else if (r0 < 1536) { w = b0w; bias = b0b; out = C0t; stride = 1; scale = 1.f; lr0 = r0 -  512; }
        else if (r0 < 2560) { w = a1w; bias = a1b; out = AX1; stride = 2; scale = L2E; lr0 = r0 - 1536; }
        else if (r0 < 3584) { w = b1w; bias = b1b; out = C1t; stride = 1; scale = 1.f; lr0 = r0 - 2560; }
        else if (r0 < 4608) { w = a2w; bias = a2b; out = AX2; stride = 2; scale = L2E; lr0 = r0 - 3584; }
        else                { w = b2w; bias = b2b; out = C2t; stride = 1; scale = 1.f; lr0 = r0 - 4608; }

        const float* __restrict__ w0 = w + (lr0 + 0) * CONDD;
        const float* __restrict__ w1 = w + (lr0 + 1) * CONDD;
        const float* __restrict__ w2 = w + (lr0 + 2) * CONDD;
        const float* __restrict__ w3 = w + (lr0 + 3) * CONDD;
        float acc0 = bias[lr0 + 0], acc1 = bias[lr0 + 1];
        float acc2 = bias[lr0 + 2], acc3 = bias[lr0 + 3];
        #pragma unroll
        for (int k = 0; k < CONDD; ++k) {
            const float uv = lds[k * 65 + b];
            acc0 = fmaf(w0[k], uv, acc0);
            acc1 = fmaf(w1[k], uv, acc1);
            acc2 = fmaf(w2[k], uv, acc2);
            acc3 = fmaf(w3[k], uv, acc3);
        }
        out[((lr0 + 0) * 64 + b) * stride] = acc0 * scale;
        out[((lr0 + 1) * 64 + b) * stride] = acc1 * scale;
        out[((lr0 + 2) * 64 + b) * stride] = acc2 * scale;
        out[((lr0 + 3) * 64 + b) * stride] = acc3 * scale;
    } else {
        // transpose one 64(b) x 64(i) tile of x into AX0 .y slots
        const int i0 = (bid - 320) * 64;
        for (int e = tid; e < 64 * 64; e += 256) {
            int r = e >> 6, c = e & 63;                // r=b, c=i offset
            lds[c * 65 + r] = x[r * NIN + i0 + c];
        }
        __syncthreads();
        for (int e = tid; e < 64 * 64; e += 256) {
            int r = e >> 6, c = e & 63;                // r=i offset, c=b
            AX0[((i0 + r) * 64 + c) * 2 + 1] = lds[r * 65 + c];
        }
    }
}

// ---------------------------------------------------------------------------
// Branchless gated masked matvec:
//   out[o,b] = sum_i 1/(1+2^(-A'[i,b]*Ct[o,b])) * m[o,i]*W[o,i] * X[i,b]
// Block: 512 threads = 8 waves splitting I 8-ways; OT o's per block.
// m/W are wave-uniform s_load streams (mask-zero terms vanish via
// exp2 overflow -> inf -> rcp -> 0, so the loop is dense and pipelines).
// ---------------------------------------------------------------------------
template<int I, int OT, bool FINAL>
__device__ __forceinline__ void gated_body(
    const float2* __restrict__ AX, const float* __restrict__ Ct,
    const float*  __restrict__ M,  const float* __restrict__ W,
    float* __restrict__ out)
{
    constexpr int ICW = I / 8;                  // i extent per wave
    const int tid = threadIdx.x;
    const int b   = tid & 63;
    const int wid = __builtin_amdgcn_readfirstlane(tid >> 6);   // 0..7 uniform
    const int o0  = blockIdx.x * OT;
    const int ibase = wid * ICW;

    float cc[OT], acc[OT];
    const float* __restrict__ mrow[OT];
    const float* __restrict__ wrow[OT];
    #pragma unroll
    for (int oo = 0; oo < OT; ++oo) {
        cc[oo]   = Ct[(o0 + oo) * 64 + b];
        mrow[oo] = M + (size_t)(o0 + oo) * I + ibase;
        wrow[oo] = W + (size_t)(o0 + oo) * I + ibase;
        acc[oo]  = 0.f;
    }
    const float2* __restrict__ axp = AX + (size_t)ibase * 64 + b;

    #pragma unroll 8
    for (int ii = 0; ii < ICW; ++ii) {
        const float2 ax = axp[(size_t)ii * 64];
        #pragma unroll
        for (int oo = 0; oo < OT; ++oo) {
            const float mw = mrow[oo][ii] * wrow[oo][ii];       // s_load * s_load
            const float t  = __builtin_amdgcn_exp2f(-(ax.x * cc[oo]));
            const float s  = __builtin_amdgcn_rcpf(1.f + t);    // inf-safe: ->0
            acc[oo] = fmaf(s, mw * ax.y, acc[oo]);
        }
    }

    __shared__ float red[8][OT][64];
    #pragma unroll
    for (int oo = 0; oo < OT; ++oo) red[wid][oo][b] = acc[oo];
    __syncthreads();
    if (tid < OT * 64) {
        const int oo = tid >> 6, bb = tid & 63;
        float v = 0.f;
        #pragma unroll
        for (int w8 = 0; w8 < 8; ++w8) v += red[w8][oo][bb];
        if (FINAL) out[bb * NOUTD + (o0 + oo)] = v;             // (B, NOUT)
        else       out[((o0 + oo) * 64 + bb) * 2 + 1] = v;      // next AX .y
    }
}

__global__ __launch_bounds__(512) void gated_l1(
    const float2* __restrict__ AX, const float* __restrict__ Ct,
    const float* __restrict__ M, const float* __restrict__ W, float* __restrict__ out)
{ gated_body<NIN, 4, false>(AX, Ct, M, W, out); }

__global__ __launch_bounds__(512) void gated_l2(
    const float2* __restrict__ AX, const float* __restrict__ Ct,
    const float* __restrict__ M, const float* __restrict__ W, float* __restrict__ out)
{ gated_body<H1D, 4, false>(AX, Ct, M, W, out); }

__global__ __launch_bounds__(512) void gated_l3(
    const float2* __restrict__ AX, const float* __restrict__ Ct,
    const float* __restrict__ M, const float* __restrict__ W, float* __restrict__ out)
{ gated_body<H2D, 2, true>(AX, Ct, M, W, out); }

// ---------------------------------------------------------------------------
extern "C" void kernel_launch(void* const* d_in, const int* in_sizes, int n_in,
                              void* d_out, int out_size, void* d_ws, size_t ws_size,
                              hipStream_t stream) {
    (void)in_sizes; (void)n_in; (void)out_size; (void)ws_size;
    const float* x   = (const float*)d_in[0];
    const float* u   = (const float*)d_in[1];
    const float* m0  = (const float*)d_in[2];
    const float* m1  = (const float*)d_in[3];
    const float* m2  = (const float*)d_in[4];
    const float* W0  = (const float*)d_in[5];
    const float* W1  = (const float*)d_in[6];
    const float* W2  = (const float*)d_in[7];
    const float* a0w = (const float*)d_in[8];  const float* a0b = (const float*)d_in[9];
    const float* b0w = (const float*)d_in[10]; const float* b0b = (const float*)d_in[11];
    const float* a1w = (const float*)d_in[12]; const float* a1b = (const float*)d_in[13];
    const float* b1w = (const float*)d_in[14]; const float* b1b = (const float*)d_in[15];
    const float* a2w = (const float*)d_in[16]; const float* a2b = (const float*)d_in[17];
    const float* b2w = (const float*)d_in[18]; const float* b2b = (const float*)d_in[19];

    float* ws  = (float*)d_ws;                 // offsets in floats
    float* AX0 = ws;                           // float2[512*64]   = 65536
    float* AX1 = ws + 65536;                   // float2[1024*64]  = 131072
    float* AX2 = ws + 196608;                  // float2[1024*64]  = 131072
    float* C0t = ws + 327680;                  // 1024*64 = 65536
    float* C1t = ws + 393216;                  // 1024*64 = 65536
    float* C2t = ws + 458752;                  // 512*64  = 32768
    float* out = (float*)d_out;

    prep_kernel<<<328, 256, 0, stream>>>(x, u,
        a0w, a0b, b0w, b0b, a1w, a1b, b1w, b1b, a2w, a2b, b2w, b2b,
        AX0, AX1, AX2, C0t, C1t, C2t);

    // L1: I=512,  O=1024, OT=4 -> 256 blocks; writes AX1 .y
    gated_l1<<<H1D / 4,   512, 0, stream>>>((const float2*)AX0, C0t, m0, W0, AX1);
    // L2: I=1024, O=1024, OT=4 -> 256 blocks; writes AX2 .y
    gated_l2<<<H2D / 4,   512, 0, stream>>>((const float2*)AX1, C1t, m1, W1, AX2);
    // L3: I=1024, O=512,  OT=2 -> 256 blocks; writes d_out (B, NOUT)
    gated_l3<<<NOUTD / 2, 512, 0, stream>>>((const float2*)AX2, C2t, m2, W2, out);
}